// Round 13
// baseline (193.078 us; speedup 1.0000x reference)
//
#include <hip/hip_runtime.h>
#include <math.h>

// BandpassFilter: out = lowpass_biquad(x) - highpass_biquad(x), f32,
// shape (32,2,220500). Exact chunked-scan parallelization of the order-2 IIR.
//
// R15: R14 with the superposition BUG FIXED. R14 ran (proving the structure
// doesn't hang -> R12's failure was infra) but absmax=0.547: the per-sample
// coefficient power scan was seeded with the CHUNK matrix M^64 (Ml00..)
// instead of the base per-sample matrix M = [[-a1,-a2],[1,0]] -> lane j
// held M^{64(j+1)} instead of M^{j+1}. Desk-checked magnitude (lowpass
// |p|=0.980: M^{64k} entries O(1)) matches the 0.547 error exactly.
// Fix: seed PL/PH with the base matrix. Cancellation audit: correct coeffs
// peak ~12, correction terms ~1.2 cancel to ~0.03, f32 term error ~7e-8 ->
// output error ~1e-6, far under threshold.
//
// Design (R12): y_exact[n] = y_zero[n] + a[n]*y(-1) + b[n]*y(-2), with
// a[n]=(M^{n+1})00, b[n]=(M^{n+1})01 identical for all chunks. Phase A
// (R10-proven staging) writes y0 in place and stores it to out (x read
// from HBM exactly once; tails bit-identical -> proven scan/lookback
// unchanged). After lookback, a 6-step shfl_up power scan gives lane j
// M^{j+1}; lanes gather their 4 fixed per-sample coeff quads. Phase C is
// a coalesced RMW correction stream over out (own region, L2-hot): load
// f4, 4 shfls for the chunk init, 16 FMAs, store. No second recurrence,
// no restage, no LDS in phase C.

namespace {

constexpr int T_LEN  = 220500;
constexpr int NCH    = 64;                          // 32 batch * 2 channels
constexpr int CHUNK  = 64;                          // samples per chunk
constexpr int NCHUNK = (T_LEN + CHUNK - 1) / CHUNK; // 3446 (last chunk = 20)
constexpr int CPB    = 256;                         // chunks per block
constexpr int BX     = (NCHUNK + CPB - 1) / CPB;    // 14 blocks along chunk dim
constexpr int NBLK   = BX * NCH;                    // 896 blocks
constexpr int HSTR   = 33;                          // 32+1: half-tile row stride
constexpr int WROW   = CHUNK * HSTR;                // 2112 floats per wave tile

struct Coeffs { float b0, b1, b2, a1, a2; };

__device__ inline Coeffs make_coeffs(float sr, float cutoff, bool hp) {
    float w0 = 6.2831853071795864f * cutoff / sr;
    float c = cosf(w0), s = sinf(w0);
    float alpha = s / (2.0f * 0.707f);
    float b0, b1;
    if (!hp) { b0 = (1.0f - c) * 0.5f; b1 = 1.0f - c; }
    else     { b0 = (1.0f + c) * 0.5f; b1 = -(1.0f + c); }
    float inv = 1.0f / (1.0f + alpha);
    Coeffs k;
    k.b0 = b0 * inv; k.b1 = b1 * inv; k.b2 = b0 * inv;
    k.a1 = (-2.0f * c) * inv;
    k.a2 = (1.0f - alpha) * inv;
    return k;
}

// one sample through both filters; returns yl - yh
__device__ inline float proc_sample(float xn, float& x1, float& x2,
                                    const Coeffs& lo, const Coeffs& hi,
                                    float& yl1, float& yl2,
                                    float& yh1, float& yh2) {
    float ffl = fmaf(lo.b0, xn, fmaf(lo.b1, x1, lo.b2 * x2));
    float tl  = fmaf(-lo.a2, yl2, ffl);
    float yl  = fmaf(-lo.a1, yl1, tl);
    float ffh = fmaf(hi.b0, xn, fmaf(hi.b1, x1, hi.b2 * x2));
    float th  = fmaf(-hi.a2, yh2, ffh);
    float yh  = fmaf(-hi.a1, yh1, th);
    yl2 = yl1; yl1 = yl;
    yh2 = yh1; yh1 = yh;
    x2 = x1; x1 = xn;
    return yl - yh;
}

// Affine map s' = A*s + c on the 2-tap IIR state s = (y[n-1], y[n-2]).
struct Aff { float a00, a01, a10, a11, c0, c1; };

__device__ inline Aff aff_id() { return {1.f, 0.f, 0.f, 1.f, 0.f, 0.f}; }

// g o f : f applied first. Same formulas as the R2/R5-verified scan.
__device__ inline Aff aff_compose(const Aff& g, const Aff& f) {
    Aff r;
    r.a00 = fmaf(g.a00, f.a00, g.a01 * f.a10);
    r.a01 = fmaf(g.a00, f.a01, g.a01 * f.a11);
    r.a10 = fmaf(g.a10, f.a00, g.a11 * f.a10);
    r.a11 = fmaf(g.a10, f.a01, g.a11 * f.a11);
    r.c0  = fmaf(g.a00, f.c0, fmaf(g.a01, f.c1, g.c0));
    r.c1  = fmaf(g.a10, f.c0, fmaf(g.a11, f.c1, g.c1));
    return r;
}

__device__ inline Aff aff_shfl_up(const Aff& e, int d) {
    Aff p;
    p.a00 = __shfl_up(e.a00, d);
    p.a01 = __shfl_up(e.a01, d);
    p.a10 = __shfl_up(e.a10, d);
    p.a11 = __shfl_up(e.a11, d);
    p.c0  = __shfl_up(e.c0, d);
    p.c1  = __shfl_up(e.c1, d);
    return p;
}

// 2x2 matrix (homogeneous part only) for the per-sample coefficient scan.
struct Mat2 { float m00, m01, m10, m11; };

__device__ inline Mat2 mat_mul(const Mat2& g, const Mat2& f) {  // g*f
    Mat2 r;
    r.m00 = fmaf(g.m00, f.m00, g.m01 * f.m10);
    r.m01 = fmaf(g.m00, f.m01, g.m01 * f.m11);
    r.m10 = fmaf(g.m10, f.m00, g.m11 * f.m10);
    r.m11 = fmaf(g.m10, f.m01, g.m11 * f.m11);
    return r;
}

// M^CHUNK for one filter: chunk transition matrix, CHUNK=64 via 6 squarings.
__device__ inline void chunk_matrix(const Coeffs& k,
                                    float& m00, float& m01,
                                    float& m10, float& m11) {
    m00 = -k.a1; m01 = -k.a2; m10 = 1.0f; m11 = 0.0f;
    #pragma unroll
    for (int i = 0; i < 6; ++i) {
        float t00 = fmaf(m00, m00, m01 * m10);
        float t01 = fmaf(m00, m01, m01 * m11);
        float t10 = fmaf(m10, m00, m11 * m10);
        float t11 = fmaf(m10, m01, m11 * m11);
        m00 = t00; m01 = t01; m10 = t10; m11 = t11;
    }
}

__global__ __launch_bounds__(256)
__attribute__((amdgpu_waves_per_eu(4, 4)))   // pin 4 waves/EU (R6 lesson):
void k_bandpass(const float* __restrict__ x, // 128-VGPR budget, no spill
                const int* __restrict__ srp,
                const float* __restrict__ clp,
                const float* __restrict__ chp,
                float* __restrict__ agg,          // [NBLK][12] aggregates
                unsigned int* __restrict__ flags, // [NBLK] 0=empty 1=ready
                float* __restrict__ out) {
    __shared__ float tile[4 * WROW];           // 33,792 B: 4 wave half-tiles
    __shared__ Aff ldsWaveL[4], ldsWaveH[4];   // wave inclusive totals
    __shared__ Aff ldsWL[4],  ldsWH[4];        // wave exclusive prefixes
    __shared__ Aff ldsLBl[BX], ldsLBh[BX];     // lookback payloads
    __shared__ float ldsCB[4];                 // block entry state (lo, hi)
    // total LDS ~34.9 KB -> 4 blocks/CU -> 1024 resident slots >= 896 (proven)

    const int t    = threadIdx.x;
    const int w    = t >> 6;
    const int lane = t & 63;
    const int ch   = blockIdx.y;
    const int bx   = blockIdx.x;
    const int pb   = bx * CPB;
    const int bid  = ch * BX + bx;

    float sr = (float)(*srp);
    Coeffs lo = make_coeffs(sr, *clp, false);
    Coeffs hi = make_coeffs(sr, *chp, true);

    const float* __restrict__ xc = x + (size_t)ch * T_LEN;
    float* __restrict__ oc = out + (size_t)ch * T_LEN;
    const int wc0 = pb + w * CHUNK;            // first chunk of this wave
    const int p   = wc0 + lane;                // this lane's chunk
    const bool active = (p < NCHUNK);
    const int s   = p * CHUNK;
    const int wbF = wc0 * CHUNK;               // wave region base (floats)

    float* __restrict__ tw = &tile[w * WROW];  // wave-private half-tile

    // x history (exact; crosses chunk/wave/block boundaries by global read)
    float x1 = (active && s >= 1) ? xc[s - 1] : 0.0f;
    float x2 = (active && s >= 2) ? xc[s - 2] : 0.0f;

    // stage half h of the wave's 64 chunks (R10-proven: 8 lanes = one
    // 128-B line, coalesced; OOB zero-filled).
    auto stageHalf = [&](int h) {
        #pragma unroll
        for (int i = 0; i < 8; ++i) {
            int f4 = i * 64 + lane;
            int c  = f4 >> 3;              // local chunk row 0..63
            int j0 = (f4 & 7) * 4;         // sample within half
            int ga = wbF + c * CHUNK + h * 32 + j0;
            float4 v = make_float4(0.f, 0.f, 0.f, 0.f);
            if (ga < T_LEN) v = *(const float4*)(xc + ga);   // T_LEN%4==0
            float* d = &tw[c * HSTR + j0];
            d[0] = v.x; d[1] = v.y; d[2] = v.z; d[3] = v.w;
        }
    };

    // ---- phase A: zero-state run; y0 = yl0-yh0 written in place and
    // stored to out (coalesced). x is read from HBM exactly once. --------
    float tl1 = 0.f, tl2 = 0.f, th1 = 0.f, th2 = 0.f;
    {
        #pragma unroll
        for (int h = 0; h < 2; ++h) {
            stageHalf(h);
            // wave-internal fence (R10-proven; rule-#18 sched fence)
            asm volatile("s_waitcnt lgkmcnt(0)" ::: "memory");
            __builtin_amdgcn_sched_barrier(0);
            {
                float* __restrict__ L = &tw[lane * HSTR];
                #pragma unroll
                for (int j = 0; j < 32; ++j)
                    L[j] = proc_sample(L[j], x1, x2, lo, hi, tl1, tl2, th1, th2);
            }
            asm volatile("s_waitcnt lgkmcnt(0)" ::: "memory");
            __builtin_amdgcn_sched_barrier(0);
            // store y0 half (coalesced 128-B lines)
            #pragma unroll
            for (int i = 0; i < 8; ++i) {
                int f4 = i * 64 + lane;
                int c  = f4 >> 3;
                int j0 = (f4 & 7) * 4;
                int ga = wbF + c * CHUNK + h * 32 + j0;
                if (ga < T_LEN) {
                    const float* sld = &tw[c * HSTR + j0];
                    *(float4*)(oc + ga) = make_float4(sld[0], sld[1], sld[2], sld[3]);
                }
            }
            // WAR fence: store's ds_reads drain before next half's ds_writes
            asm volatile("s_waitcnt lgkmcnt(0)" ::: "memory");
            __builtin_amdgcn_sched_barrier(0);
        }
    }
    // tails (tl1,tl2,th1,th2) are bit-identical to R10 -> scan unchanged.

    // ---- block-level affine scan over the 256 per-chunk maps (proven) ---
    float Ml00, Ml01, Ml10, Ml11, Mh00, Mh01, Mh10, Mh11;
    chunk_matrix(lo, Ml00, Ml01, Ml10, Ml11);
    chunk_matrix(hi, Mh00, Mh01, Mh10, Mh11);

    Aff il = active ? Aff{Ml00, Ml01, Ml10, Ml11, tl1, tl2} : aff_id();
    Aff ih = active ? Aff{Mh00, Mh01, Mh10, Mh11, th1, th2} : aff_id();

    #pragma unroll
    for (int d = 1; d < 64; d <<= 1) {
        Aff plx = aff_shfl_up(il, d);
        Aff phx = aff_shfl_up(ih, d);
        if (lane >= d) {
            il = aff_compose(il, plx);
            ih = aff_compose(ih, phx);
        }
    }
    if (lane == 63) { ldsWaveL[w] = il; ldsWaveH[w] = ih; }
    __syncthreads();

    if (t == 0) {
        Aff rl = aff_id(), rh = aff_id();
        #pragma unroll
        for (int ww = 0; ww < 4; ++ww) {
            ldsWL[ww] = rl; ldsWH[ww] = rh;
            rl = aff_compose(ldsWaveL[ww], rl);
            rh = aff_compose(ldsWaveH[ww], rh);
        }
        // publish block aggregate (proven R5 protocol)
        float* pl = agg + (size_t)bid * 12;
        __hip_atomic_store(pl + 0,  rl.a00, __ATOMIC_RELAXED, __HIP_MEMORY_SCOPE_AGENT);
        __hip_atomic_store(pl + 1,  rl.a01, __ATOMIC_RELAXED, __HIP_MEMORY_SCOPE_AGENT);
        __hip_atomic_store(pl + 2,  rl.a10, __ATOMIC_RELAXED, __HIP_MEMORY_SCOPE_AGENT);
        __hip_atomic_store(pl + 3,  rl.a11, __ATOMIC_RELAXED, __HIP_MEMORY_SCOPE_AGENT);
        __hip_atomic_store(pl + 4,  rl.c0,  __ATOMIC_RELAXED, __HIP_MEMORY_SCOPE_AGENT);
        __hip_atomic_store(pl + 5,  rl.c1,  __ATOMIC_RELAXED, __HIP_MEMORY_SCOPE_AGENT);
        __hip_atomic_store(pl + 6,  rh.a00, __ATOMIC_RELAXED, __HIP_MEMORY_SCOPE_AGENT);
        __hip_atomic_store(pl + 7,  rh.a01, __ATOMIC_RELAXED, __HIP_MEMORY_SCOPE_AGENT);
        __hip_atomic_store(pl + 8,  rh.a10, __ATOMIC_RELAXED, __HIP_MEMORY_SCOPE_AGENT);
        __hip_atomic_store(pl + 9,  rh.a11, __ATOMIC_RELAXED, __HIP_MEMORY_SCOPE_AGENT);
        __hip_atomic_store(pl + 10, rh.c0,  __ATOMIC_RELAXED, __HIP_MEMORY_SCOPE_AGENT);
        __hip_atomic_store(pl + 11, rh.c1,  __ATOMIC_RELAXED, __HIP_MEMORY_SCOPE_AGENT);
        __hip_atomic_store(&flags[bid], 1u, __ATOMIC_RELEASE, __HIP_MEMORY_SCOPE_AGENT);
    }
    __syncthreads();

    // per-thread block-exclusive prefix = (wave-exclusive of thread) o W[wave]
    Aff exL, exH;
    {
        Aff pl_ = aff_shfl_up(il, 1);
        Aff ph_ = aff_shfl_up(ih, 1);
        if (lane == 0) { pl_ = aff_id(); ph_ = aff_id(); }
        exL = aff_compose(pl_, ldsWL[w]);
        exH = aff_compose(ph_, ldsWH[w]);
    }

    // ---- lookback: wave 0 polls the <=13 predecessors (proven R5-R11) ---
    if (bx > 0) {
        if (t < bx) {
            int idx = ch * BX + t;
            int spins = 0;
            for (;;) {
                unsigned int f = (spins < 1024)
                    ? __hip_atomic_load(&flags[idx], __ATOMIC_RELAXED,
                                        __HIP_MEMORY_SCOPE_SYSTEM)
                    : __hip_atomic_load(&flags[idx], __ATOMIC_ACQUIRE,
                                        __HIP_MEMORY_SCOPE_AGENT);
                if (f != 0u) break;
                __builtin_amdgcn_s_sleep(2);   // constant (R13 compile fix)
                ++spins;
            }
            (void)__hip_atomic_load(&flags[idx], __ATOMIC_ACQUIRE,
                                    __HIP_MEMORY_SCOPE_AGENT);
            const float* pp = agg + (size_t)idx * 12;
            Aff al, ah;
            al.a00 = __hip_atomic_load(pp + 0,  __ATOMIC_RELAXED, __HIP_MEMORY_SCOPE_AGENT);
            al.a01 = __hip_atomic_load(pp + 1,  __ATOMIC_RELAXED, __HIP_MEMORY_SCOPE_AGENT);
            al.a10 = __hip_atomic_load(pp + 2,  __ATOMIC_RELAXED, __HIP_MEMORY_SCOPE_AGENT);
            al.a11 = __hip_atomic_load(pp + 3,  __ATOMIC_RELAXED, __HIP_MEMORY_SCOPE_AGENT);
            al.c0  = __hip_atomic_load(pp + 4,  __ATOMIC_RELAXED, __HIP_MEMORY_SCOPE_AGENT);
            al.c1  = __hip_atomic_load(pp + 5,  __ATOMIC_RELAXED, __HIP_MEMORY_SCOPE_AGENT);
            ah.a00 = __hip_atomic_load(pp + 6,  __ATOMIC_RELAXED, __HIP_MEMORY_SCOPE_AGENT);
            ah.a01 = __hip_atomic_load(pp + 7,  __ATOMIC_RELAXED, __HIP_MEMORY_SCOPE_AGENT);
            ah.a10 = __hip_atomic_load(pp + 8,  __ATOMIC_RELAXED, __HIP_MEMORY_SCOPE_AGENT);
            ah.a11 = __hip_atomic_load(pp + 9,  __ATOMIC_RELAXED, __HIP_MEMORY_SCOPE_AGENT);
            ah.c0  = __hip_atomic_load(pp + 10, __ATOMIC_RELAXED, __HIP_MEMORY_SCOPE_AGENT);
            ah.c1  = __hip_atomic_load(pp + 11, __ATOMIC_RELAXED, __HIP_MEMORY_SCOPE_AGENT);
            ldsLBl[t] = al; ldsLBh[t] = ah;
        }
        __syncthreads();
        if (t == 0) {
            Aff rl = ldsLBl[0], rh = ldsLBh[0];
            for (int l = 1; l < bx; ++l) {
                rl = aff_compose(ldsLBl[l], rl);
                rh = aff_compose(ldsLBh[l], rh);
            }
            ldsCB[0] = rl.c0; ldsCB[1] = rl.c1;   // entry state = prefix(0)
            ldsCB[2] = rh.c0; ldsCB[3] = rh.c1;
        }
        __syncthreads();
    } else if (t == 0) {
        ldsCB[0] = 0.f; ldsCB[1] = 0.f; ldsCB[2] = 0.f; ldsCB[3] = 0.f;
    }
    if (bx == 0) __syncthreads();

    const float cbl0 = ldsCB[0], cbl1 = ldsCB[1];
    const float cbh0 = ldsCB[2], cbh1 = ldsCB[3];

    // exact init state for this thread's chunk: ex(cb)  (= y[-1], y[-2])
    float yl1 = fmaf(exL.a00, cbl0, fmaf(exL.a01, cbl1, exL.c0));
    float yl2 = fmaf(exL.a10, cbl0, fmaf(exL.a11, cbl1, exL.c1));
    float yh1 = fmaf(exH.a00, cbh0, fmaf(exH.a01, cbh1, exH.c0));
    float yh2 = fmaf(exH.a10, cbh0, fmaf(exH.a11, cbh1, exH.c1));

    // ---- per-sample coefficient tables: lane j holds M^{j+1} after a
    // 6-step shfl_up power scan seeded with the BASE per-sample matrix
    // M = [[-a1,-a2],[1,0]] (R14 bug: was seeded with the chunk matrix
    // M^64). alpha[j]=(M^{j+1})00, beta[j]=(M^{j+1})01. Each lane gathers
    // coeffs for its 4 FIXED sample indices j0=(lane&15)*4 .. +3.
    Mat2 PL = {-lo.a1, -lo.a2, 1.0f, 0.0f};   // base M, NOT M^64
    Mat2 PH = {-hi.a1, -hi.a2, 1.0f, 0.0f};
    #pragma unroll
    for (int d = 1; d < 64; d <<= 1) {
        Mat2 ql, qh;
        ql.m00 = __shfl_up(PL.m00, d); ql.m01 = __shfl_up(PL.m01, d);
        ql.m10 = __shfl_up(PL.m10, d); ql.m11 = __shfl_up(PL.m11, d);
        qh.m00 = __shfl_up(PH.m00, d); qh.m01 = __shfl_up(PH.m01, d);
        qh.m10 = __shfl_up(PH.m10, d); qh.m11 = __shfl_up(PH.m11, d);
        if (lane >= d) { PL = mat_mul(PL, ql); PH = mat_mul(PH, qh); }
    }
    const int j0 = (lane & 15) * 4;
    float tAl[4], tBl[4], tAh[4], tBh[4];   // hi pre-negated
    #pragma unroll
    for (int k = 0; k < 4; ++k) {
        tAl[k] =  __shfl(PL.m00, j0 + k);
        tBl[k] =  __shfl(PL.m01, j0 + k);
        tAh[k] = -__shfl(PH.m00, j0 + k);
        tBh[k] = -__shfl(PH.m01, j0 + k);
    }

    // ---- phase C: coalesced RMW correction stream over out (L2-hot).
    // out_exact = y0 + al*sl1 + bl*sl2 - ah*sh1 - bh*sh2. Chunk init
    // shuffled from lane c (local chunk index) each iteration.
    asm volatile("s_waitcnt vmcnt(0)" ::: "memory");  // y0 stores drained
    #pragma unroll
    for (int i = 0; i < 16; ++i) {
        int f  = i * 256 + lane * 4;
        int ga = wbF + f;
        int cl = i * 4 + (lane >> 4);      // local chunk of this quad
        float A = __shfl(yl1, cl);
        float B = __shfl(yl2, cl);
        float C = __shfl(yh1, cl);
        float D = __shfl(yh2, cl);
        if (ga < T_LEN) {
            float4 v = *(const float4*)(oc + ga);
            v.x = fmaf(tAl[0], A, fmaf(tBl[0], B, fmaf(tAh[0], C, fmaf(tBh[0], D, v.x))));
            v.y = fmaf(tAl[1], A, fmaf(tBl[1], B, fmaf(tAh[1], C, fmaf(tBh[1], D, v.y))));
            v.z = fmaf(tAl[2], A, fmaf(tBl[2], B, fmaf(tAh[2], C, fmaf(tBh[2], D, v.z))));
            v.w = fmaf(tAl[3], A, fmaf(tBl[3], B, fmaf(tAh[3], C, fmaf(tBh[3], D, v.w))));
            *(float4*)(oc + ga) = v;
        }
    }
}

} // namespace

extern "C" void kernel_launch(void* const* d_in, const int* in_sizes, int n_in,
                              void* d_out, int out_size, void* d_ws, size_t ws_size,
                              hipStream_t stream) {
    const float* audio = (const float*)d_in[0];
    const int*   srp   = (const int*)d_in[1];
    const float* clp   = (const float*)d_in[2];
    const float* chp   = (const float*)d_in[3];
    float* out = (float*)d_out;

    // ws layout (R5-R11 proven): [NBLK] u32 flags | pad to 4096 B |
    //                            [NBLK][12] f32 aggregates
    unsigned int* flags = (unsigned int*)d_ws;
    float* agg = (float*)((char*)d_ws + 4096);
    // ws needed: 4096 + 896*48 B ~= 47 KB

    (void)hipMemsetAsync(flags, 0, NBLK * sizeof(unsigned int), stream);

    dim3 grid(BX, NCH);   // 14 x 64 = 896 blocks; capacity 4/CU * 256 = 1024
    hipLaunchKernelGGL(k_bandpass, grid, dim3(256), 0, stream,
                       audio, srp, clp, chp, agg, flags, out);
}